// Round 11
// baseline (112.618 us; speedup 1.0000x reference)
//
#include <hip/hip_runtime.h>
#include <hip/hip_bf16.h>

// Problem constants (B,G,D,H,K,V) = (4, 2048, 128, 8, 16, 16)
#define GG 2048
#define DD 128
#define HH 8
#define BH 32

typedef _Float16 h2 __attribute__((ext_vector_type(2)));
typedef _Float16 h4 __attribute__((ext_vector_type(4)));
typedef _Float16 h8 __attribute__((ext_vector_type(8)));
typedef __attribute__((ext_vector_type(4))) float f32x4;
typedef unsigned short u16;
typedef unsigned int   u32;
typedef unsigned char  u8;
typedef unsigned long long u64;

// 0.25 (=1/sqrt(16)) * log2(e): folded into W_Q so softmax uses raw exp2.
#define QSCALE 0.36067376022224085f

// ws layout: 6.5 MB
#define OFF_Q  0u           // f16 Qh [BH][G][16] (scaled)                    2 MB
#define OFF_KV (2u << 20)   // u8  KVp [BH][16 tiles][8192]: K(128x16) | V^T  4 MB
#define OFF_M  (6u << 20)   // u8  mbt [16][G][16] transposed mask bits     512 KB

#if __has_builtin(__builtin_amdgcn_exp2f)
#define EXP2F(x) __builtin_amdgcn_exp2f(x)
#else
#define EXP2F(x) exp2f(x)
#endif

// Legacy K=16 f16 MFMA (no underscore before f16 — gfx908-era naming).
#define MFMA16(a, b, c) __builtin_amdgcn_mfma_f32_16x16x16f16(a, b, c, 0, 0, 0)

static __device__ __forceinline__ u16 f16b(float x) {
  return __builtin_bit_cast(u16, (_Float16)x);
}

// ---------------------------------------------------------------------------
// Kernel 1 (fused prep): unchanged from round 10 (verified).
//  blocks [0,256):   MFMA projection -> Qh + packed KV tiles (8 KB per
//                    (bh, 128-key tile): K [128][16] f16 | V^T [16][128]
//                    chunk-swizzled).
//  blocks [256,2304): mask int32 -> transposed byte map mbt[g8][q][16].
// ---------------------------------------------------------------------------
__global__ __launch_bounds__(256) void prep_kernel(
    const float* __restrict__ h, const int* __restrict__ mask,
    const float* __restrict__ WQ, const float* __restrict__ WK,
    const float* __restrict__ WV,
    _Float16* __restrict__ Qh, u8* __restrict__ KVp, u8* __restrict__ mbt)
{
  const int blk = blockIdx.x, tid = threadIdx.x;

  if (blk >= 256) {                      // ---- mask -> transposed byte map ----
    int t = (blk - 256) * 256 + tid;     // [0, 524288)
    const int* m = mask + (size_t)t * 8;
    int4 m0 = *(const int4*)m;
    int4 m1 = *(const int4*)(m + 4);
    u32 byte = (m0.x > 0) | ((m0.y > 0) << 1) | ((m0.z > 0) << 2) | ((m0.w > 0) << 3)
             | ((m1.x > 0) << 4) | ((m1.y > 0) << 5) | ((m1.z > 0) << 6) | ((m1.w > 0) << 7);
    int q  = t >> 8;          // mask row
    int k8 = t & 255;         // byte index within row (keys k8*8..+7)
    mbt[(size_t)(k8 >> 4) * (GG * 16) + (size_t)q * 16 + (k8 & 15)] = (u8)byte;
    return;
  }

  // ---- projection: 8 blocks/bh, 4 waves/block, 64 g-rows/wave ----
  __shared__ _Float16 Wl[48 * 136];      // [n 48][d 128 pad 136]
  const int bh = blk >> 3, b = bh >> 3, hh = bh & (HH - 1);

  #pragma unroll
  for (int m = 0; m < 3; ++m) {
    const float* W = (m == 0 ? WQ : (m == 1 ? WK : WV)) + (size_t)hh * DD * 16;
    const float sc = (m == 0) ? QSCALE : 1.0f;
    #pragma unroll
    for (int i = 0; i < 2; ++i) {
      int j4 = i * 256 + tid;
      float4 v = ((const float4*)W)[j4];
      int j = j4 * 4, d = j >> 4, n0 = m * 16 + (j & 15);
      Wl[(n0 + 0) * 136 + d] = (_Float16)(v.x * sc);
      Wl[(n0 + 1) * 136 + d] = (_Float16)(v.y * sc);
      Wl[(n0 + 2) * 136 + d] = (_Float16)(v.z * sc);
      Wl[(n0 + 3) * 136 + d] = (_Float16)(v.w * sc);
    }
  }
  __syncthreads();

  const int wave = tid >> 6, lane = tid & 63;
  const int col = lane & 15, quad = lane >> 4;
  const int g0 = ((blk & 7) * 4 + wave) * 64;
  const float* hb = h + (size_t)b * GG * DD;

  f32x4 acc[4][3];
  #pragma unroll
  for (int mt = 0; mt < 4; ++mt)
    #pragma unroll
    for (int nt = 0; nt < 3; ++nt)
      acc[mt][nt] = (f32x4){0.f, 0.f, 0.f, 0.f};

  #pragma unroll
  for (int s = 0; s < 4; ++s) {
    h8 a[4], bw[3];
    #pragma unroll
    for (int mt = 0; mt < 4; ++mt) {
      const float* src = hb + (size_t)(g0 + mt * 16 + col) * DD + s * 32 + quad * 8;
      float4 x = ((const float4*)src)[0];
      float4 y = ((const float4*)src)[1];
      a[mt] = (h8){ (_Float16)x.x, (_Float16)x.y, (_Float16)x.z, (_Float16)x.w,
                    (_Float16)y.x, (_Float16)y.y, (_Float16)y.z, (_Float16)y.w };
    }
    #pragma unroll
    for (int nt = 0; nt < 3; ++nt)
      bw[nt] = *(const h8*)&Wl[(nt * 16 + col) * 136 + s * 32 + quad * 8];
    #pragma unroll
    for (int mt = 0; mt < 4; ++mt)
      #pragma unroll
      for (int nt = 0; nt < 3; ++nt)
        acc[mt][nt] = __builtin_amdgcn_mfma_f32_16x16x32_f16(a[mt], bw[nt], acc[mt][nt], 0, 0, 0);
  }

  u8* kvb = KVp + (size_t)bh * 16 * 8192;
  #pragma unroll
  for (int mt = 0; mt < 4; ++mt) {
    #pragma unroll
    for (int r = 0; r < 4; ++r) {
      int g = g0 + mt * 16 + quad * 4 + r;
      Qh[((size_t)bh * GG + g) * 16 + col] = (_Float16)acc[mt][0][r];
      int gi = g & 127;
      u8* tb = kvb + (size_t)(g >> 7) * 8192;
      *(u16*)(tb + gi * 32 + col * 2) = f16b(acc[mt][1][r]);                 // K
      *(u16*)(tb + 4096 + col * 256 + ((((gi >> 2) + col) & 31) * 8)
                 + (g & 3) * 2) = f16b(acc[mt][2][r]);                       // V^T swizzled
    }
  }
}

// ---------------------------------------------------------------------------
// Kernel 2: flash attention, cooperative LDS staging, 2 tiles per stage.
// Block = 512 thr (8 waves, 16 q each, 128 q/block); 512 blocks = 2 blocks/CU
// = 4 waves/SIMD (same as r10) but: staging traffic halved (64 MB L2 total),
// barriers 15 -> 7 per block, prefetch-to-use distance = 2 tiles of compute
// (~800+ cyc, fully covers L2 latency). Mask words pre-shifted by quad*4 per
// tile -> constant-shift extracts in the unrolled sub-tile loop.
// XCD swizzle (bh = blk & 31) keeps each bh's KV on one XCD.
// ---------------------------------------------------------------------------
__global__ __launch_bounds__(512, 4) void attn_kernel(
    const _Float16* __restrict__ Qh, const u8* __restrict__ KVp,
    const u8* __restrict__ mbt, float* __restrict__ out)
{
  __shared__ __align__(16) u8 kv[2][16384];    // 2 buffers x 2 tiles
  const int tid = threadIdx.x, wv = tid >> 6, lane = tid & 63;
  const int col = lane & 15, quad = lane >> 4;
  const int bh = blockIdx.x & 31;              // XCD swizzle
  const int qb = (blockIdx.x >> 5) * 128 + wv * 16;

  // Q B-frag (16x16x16): n=col, k=quad*4+j -> 8B load
  const h4 qf = *(const h4*)(Qh + ((size_t)bh * GG + qb + col) * 16 + quad * 4);
  const u8* kvsrc = KVp + (size_t)bh * 16 * 8192;
  const u8* mrow  = mbt + (size_t)(qb + col) * 16;

  f32x4 acc = {0.f,0.f,0.f,0.f}, lacc = {0.f,0.f,0.f,0.f};
  const f32x4 cinit = {-4.f, -4.f, -4.f, -4.f};
  const h4 ones = {(_Float16)1.f, (_Float16)1.f, (_Float16)1.f, (_Float16)1.f};
  const int shq = quad * 4;

  // one 128-key tile: 8 sub-tiles from LDS (K rows + swizzled V^T), mask mv
  auto tile = [&](const u8* cur, uint4 mv) {
    const _Float16* ldsK = (const _Float16*)cur;
    const u8* ldsV = cur + 4096;
    u64 w0 = ((u64)mv.x | ((u64)mv.y << 32)) >> shq;   // keys 0..63, pre-shifted
    u64 w1 = ((u64)mv.z | ((u64)mv.w << 32)) >> shq;   // keys 64..127
    #pragma unroll
    for (int st = 0; st < 8; ++st) {
      h4 kf = *(const h4*)(ldsK + (size_t)(st * 16 + col) * 16 + quad * 4);
      h4 vf = *(const h4*)(ldsV + col * 256 + (((st * 4 + quad + col) & 31) * 8));

      f32x4 s = MFMA16(kf, qf, cinit);         // S^T[key][q=col], -4 shift
      u32 bits = (u32)(((st < 4) ? w0 : w1) >> ((st & 3) * 16)) & 0xFu;
      float p0 = (bits & 1u) ? 0.f : EXP2F(s[0]);
      float p1 = (bits & 2u) ? 0.f : EXP2F(s[1]);
      float p2 = (bits & 4u) ? 0.f : EXP2F(s[2]);
      float p3 = (bits & 8u) ? 0.f : EXP2F(s[3]);

      h2 a01 = __builtin_bit_cast(h2, __builtin_amdgcn_cvt_pkrtz(p0, p1));
      h2 a23 = __builtin_bit_cast(h2, __builtin_amdgcn_cvt_pkrtz(p2, p3));
      h4 pf = __builtin_shufflevector(a01, a23, 0, 1, 2, 3);

      acc  = MFMA16(vf, pf, acc);              // O^T[vdim][q]
      lacc = MFMA16(ones, pf, lacc);           // denominator (MFMA pipe)
    }
  };

  // prologue: stage tiles {0,1} into kv[0] (512 thr x 32 B = 16 KB)
  {
    uint4 a0 = *(const uint4*)(kvsrc + tid * 32);
    uint4 a1 = *(const uint4*)(kvsrc + tid * 32 + 16);
    *(uint4*)(kv[0] + tid * 32) = a0;
    *(uint4*)(kv[0] + tid * 32 + 16) = a1;
  }
  uint4 mv0 = *(const uint4*)mrow;
  uint4 mv1 = *(const uint4*)(mrow + (size_t)(GG * 16));
  __syncthreads();

  for (int it = 0; it < 8; ++it) {             // 8 stages x 2 tiles
    uint4 na0, na1, nm0, nm1;
    if (it < 7) {                              // prefetch next 2 tiles
      const u8* ns = kvsrc + (size_t)(it + 1) * 16384 + tid * 32;
      na0 = *(const uint4*)ns;
      na1 = *(const uint4*)(ns + 16);
      nm0 = *(const uint4*)(mrow + (size_t)(2 * it + 2) * (GG * 16));
      nm1 = *(const uint4*)(mrow + (size_t)(2 * it + 3) * (GG * 16));
    }

    const u8* cur = kv[it & 1];
    tile(cur, mv0);                            // tile 2it
    tile(cur + 8192, mv1);                     // tile 2it+1

    if (it < 7) {
      // write buffer (it+1)&1: its last readers passed the previous barrier
      u8* nb = kv[(it + 1) & 1];
      *(uint4*)(nb + tid * 32) = na0;
      *(uint4*)(nb + tid * 32 + 16) = na1;
      mv0 = nm0; mv1 = nm1;
      __syncthreads();
    }
  }

  const float l = lacc[0];                     // sum_k P[k][col], all 2048 keys
  const float rl = (l > 0.f) ? (1.f / l) : 0.f;     // all-masked row -> 0 (ref)
  float4 o = { acc[0] * rl, acc[1] * rl, acc[2] * rl, acc[3] * rl };
  *(float4*)(out + ((size_t)bh * GG + qb + col) * 16 + quad * 4) = o;
}

// ---------------------------------------------------------------------------
extern "C" void kernel_launch(void* const* d_in, const int* in_sizes, int n_in,
                              void* d_out, int out_size, void* d_ws, size_t ws_size,
                              hipStream_t stream) {
  const float* h    = (const float*)d_in[0];
  const int*   mask = (const int*)d_in[1];
  const float* WQ   = (const float*)d_in[2];
  const float* WK   = (const float*)d_in[3];
  const float* WV   = (const float*)d_in[4];
  float* out = (float*)d_out;
  char* ws = (char*)d_ws;     // uses 6.5 MB
  _Float16* Qh  = (_Float16*)(ws + OFF_Q);
  u8*       KVp = (u8*)(ws + OFF_KV);
  u8*       mbt = (u8*)(ws + OFF_M);

  hipLaunchKernelGGL(prep_kernel, dim3(256 + GG * GG / (256 * 8)), dim3(256), 0, stream,
                     h, mask, WQ, WK, WV, Qh, KVp, mbt);
  hipLaunchKernelGGL(attn_kernel, dim3(BH * (GG / 128)), dim3(512), 0, stream,
                     Qh, KVp, mbt, out);
}

// Round 12
// 107.797 us; speedup vs baseline: 1.0447x; 1.0447x over previous
//
#include <hip/hip_runtime.h>
#include <hip/hip_bf16.h>

// Problem constants (B,G,D,H,K,V) = (4, 2048, 128, 8, 16, 16)
#define GG 2048
#define DD 128
#define HH 8
#define BH 32

typedef _Float16 h2 __attribute__((ext_vector_type(2)));
typedef _Float16 h4 __attribute__((ext_vector_type(4)));
typedef _Float16 h8 __attribute__((ext_vector_type(8)));
typedef __attribute__((ext_vector_type(4))) float f32x4;
typedef unsigned short u16;
typedef unsigned int   u32;
typedef unsigned char  u8;
typedef unsigned long long u64;

// 0.25 (=1/sqrt(16)) * log2(e): folded into W_Q so softmax uses raw exp2.
#define QSCALE 0.36067376022224085f

// ws layout: 6.5 MB
#define OFF_Q  0u           // f16 Qh [BH][G][16] (scaled)                    2 MB
#define OFF_KV (2u << 20)   // u8  KVp [BH][16 tiles][8192]: K(128x16) | V^T  4 MB
#define OFF_M  (6u << 20)   // u8  mbt [16][G][16] transposed mask bits     512 KB

#if __has_builtin(__builtin_amdgcn_exp2f)
#define EXP2F(x) __builtin_amdgcn_exp2f(x)
#else
#define EXP2F(x) exp2f(x)
#endif

// Legacy K=16 f16 MFMA (no underscore before f16 — gfx908-era naming).
#define MFMA16(a, b, c) __builtin_amdgcn_mfma_f32_16x16x16f16(a, b, c, 0, 0, 0)

static __device__ __forceinline__ u16 f16b(float x) {
  return __builtin_bit_cast(u16, (_Float16)x);
}

// ---------------------------------------------------------------------------
// Kernel 1 (fused prep): unchanged from round 10/11 (verified).
//  blocks [0,256):   MFMA projection -> Qh + packed KV tiles (8 KB per
//                    (bh, 128-key tile): K [128][16] f16 | V^T [16][128]
//                    chunk-swizzled).
//  blocks [256,2304): mask int32 -> transposed byte map mbt[g8][q][16].
// ---------------------------------------------------------------------------
__global__ __launch_bounds__(256) void prep_kernel(
    const float* __restrict__ h, const int* __restrict__ mask,
    const float* __restrict__ WQ, const float* __restrict__ WK,
    const float* __restrict__ WV,
    _Float16* __restrict__ Qh, u8* __restrict__ KVp, u8* __restrict__ mbt)
{
  const int blk = blockIdx.x, tid = threadIdx.x;

  if (blk >= 256) {                      // ---- mask -> transposed byte map ----
    int t = (blk - 256) * 256 + tid;     // [0, 524288)
    const int* m = mask + (size_t)t * 8;
    int4 m0 = *(const int4*)m;
    int4 m1 = *(const int4*)(m + 4);
    u32 byte = (m0.x > 0) | ((m0.y > 0) << 1) | ((m0.z > 0) << 2) | ((m0.w > 0) << 3)
             | ((m1.x > 0) << 4) | ((m1.y > 0) << 5) | ((m1.z > 0) << 6) | ((m1.w > 0) << 7);
    int q  = t >> 8;          // mask row
    int k8 = t & 255;         // byte index within row (keys k8*8..+7)
    mbt[(size_t)(k8 >> 4) * (GG * 16) + (size_t)q * 16 + (k8 & 15)] = (u8)byte;
    return;
  }

  // ---- projection: 8 blocks/bh, 4 waves/block, 64 g-rows/wave ----
  __shared__ _Float16 Wl[48 * 136];      // [n 48][d 128 pad 136]
  const int bh = blk >> 3, b = bh >> 3, hh = bh & (HH - 1);

  #pragma unroll
  for (int m = 0; m < 3; ++m) {
    const float* W = (m == 0 ? WQ : (m == 1 ? WK : WV)) + (size_t)hh * DD * 16;
    const float sc = (m == 0) ? QSCALE : 1.0f;
    #pragma unroll
    for (int i = 0; i < 2; ++i) {
      int j4 = i * 256 + tid;
      float4 v = ((const float4*)W)[j4];
      int j = j4 * 4, d = j >> 4, n0 = m * 16 + (j & 15);
      Wl[(n0 + 0) * 136 + d] = (_Float16)(v.x * sc);
      Wl[(n0 + 1) * 136 + d] = (_Float16)(v.y * sc);
      Wl[(n0 + 2) * 136 + d] = (_Float16)(v.z * sc);
      Wl[(n0 + 3) * 136 + d] = (_Float16)(v.w * sc);
    }
  }
  __syncthreads();

  const int wave = tid >> 6, lane = tid & 63;
  const int col = lane & 15, quad = lane >> 4;
  const int g0 = ((blk & 7) * 4 + wave) * 64;
  const float* hb = h + (size_t)b * GG * DD;

  f32x4 acc[4][3];
  #pragma unroll
  for (int mt = 0; mt < 4; ++mt)
    #pragma unroll
    for (int nt = 0; nt < 3; ++nt)
      acc[mt][nt] = (f32x4){0.f, 0.f, 0.f, 0.f};

  #pragma unroll
  for (int s = 0; s < 4; ++s) {
    h8 a[4], bw[3];
    #pragma unroll
    for (int mt = 0; mt < 4; ++mt) {
      const float* src = hb + (size_t)(g0 + mt * 16 + col) * DD + s * 32 + quad * 8;
      float4 x = ((const float4*)src)[0];
      float4 y = ((const float4*)src)[1];
      a[mt] = (h8){ (_Float16)x.x, (_Float16)x.y, (_Float16)x.z, (_Float16)x.w,
                    (_Float16)y.x, (_Float16)y.y, (_Float16)y.z, (_Float16)y.w };
    }
    #pragma unroll
    for (int nt = 0; nt < 3; ++nt)
      bw[nt] = *(const h8*)&Wl[(nt * 16 + col) * 136 + s * 32 + quad * 8];
    #pragma unroll
    for (int mt = 0; mt < 4; ++mt)
      #pragma unroll
      for (int nt = 0; nt < 3; ++nt)
        acc[mt][nt] = __builtin_amdgcn_mfma_f32_16x16x32_f16(a[mt], bw[nt], acc[mt][nt], 0, 0, 0);
  }

  u8* kvb = KVp + (size_t)bh * 16 * 8192;
  #pragma unroll
  for (int mt = 0; mt < 4; ++mt) {
    #pragma unroll
    for (int r = 0; r < 4; ++r) {
      int g = g0 + mt * 16 + quad * 4 + r;
      Qh[((size_t)bh * GG + g) * 16 + col] = (_Float16)acc[mt][0][r];
      int gi = g & 127;
      u8* tb = kvb + (size_t)(g >> 7) * 8192;
      *(u16*)(tb + gi * 32 + col * 2) = f16b(acc[mt][1][r]);                 // K
      *(u16*)(tb + 4096 + col * 256 + ((((gi >> 2) + col) & 31) * 8)
                 + (g & 3) * 2) = f16b(acc[mt][2][r]);                       // V^T swizzled
    }
  }
}

// ---------------------------------------------------------------------------
// Kernel 2: flash attention — LDS staging (r10/11) + in-block split-K with
// 2 q-fragments per wave (r9) for 2x per-wave ILP at constant occupancy.
// 512-thr blocks: 8 waves = 4 q-pairs (32 q) x 2 key-halves (1024 keys).
// Grid 512 -> 4096 waves = 4 waves/SIMD, 2 blocks/CU (LDS ~42 KB).
// Staging: threads 0-255 stage half-0's tile, 256-511 half-1's (16 KB/stage,
// 7 barriers); each wave reads fragments from its half's LDS tile — shared
// kf/vf ds_reads feed TWO independent S->exp->pack->PV chains (r11 showed the
// bottleneck is this chain's latency, not staging BW or barriers).
// Denominator via ones-MFMA; split-K merge via LDS partials + one barrier
// (verified in r9). XCD swizzle keeps each bh's KV on one XCD.
// ---------------------------------------------------------------------------
__global__ __launch_bounds__(512, 4) void attn_kernel(
    const _Float16* __restrict__ Qh, const u8* __restrict__ KVp,
    const u8* __restrict__ mbt, float* __restrict__ out)
{
  __shared__ __align__(16) u8 kv[2][16384];   // [stage parity][half 8KB x 2]
  __shared__ float Lacc[4][32][17];           // merge: [q-pair][q][vdim pad]
  __shared__ float Ll[4][32];
  const int tid = threadIdx.x, wv = tid >> 6, lane = tid & 63;
  const int col = lane & 15, quad = lane >> 4;
  const int g  = wv & 3;               // q-pair index
  const int kh = wv >> 2;              // key half (0: keys 0..1023, 1: rest)
  const int bh = blockIdx.x & 31;      // XCD swizzle
  const int qb = (blockIdx.x >> 5) * 128 + g * 32;

  // Q B-frags (16x16x16): n=col, k=quad*4+j -> 8B loads
  const h4 qf0 = *(const h4*)(Qh + ((size_t)bh * GG + qb + col) * 16 + quad * 4);
  const h4 qf1 = *(const h4*)(Qh + ((size_t)bh * GG + qb + 16 + col) * 16 + quad * 4);

  const u8* kvsrc = KVp + (size_t)bh * 16 * 8192;
  const u8* mr0 = mbt + (size_t)(qb + col) * 16;
  const u8* mr1 = mbt + (size_t)(qb + 16 + col) * 16;

  f32x4 acc0 = {0.f,0.f,0.f,0.f}, acc1 = {0.f,0.f,0.f,0.f};
  f32x4 lacc0 = {0.f,0.f,0.f,0.f}, lacc1 = {0.f,0.f,0.f,0.f};
  const f32x4 cinit = {-4.f, -4.f, -4.f, -4.f};
  const h4 ones = {(_Float16)1.f, (_Float16)1.f, (_Float16)1.f, (_Float16)1.f};
  const int shq = quad * 4;

  // staging role: threads 0-255 stage half-0 tiles (it), 256-511 half-1 (8+it)
  const int sthalf = tid >> 8, sttid = tid & 255;

  // prologue: stage tiles {0, 8} + this wave's tile masks
  {
    const u8* s0 = kvsrc + (size_t)(sthalf * 8) * 8192 + sttid * 32;
    *(uint4*)(kv[0] + sthalf * 8192 + sttid * 32) = *(const uint4*)s0;
    *(uint4*)(kv[0] + sthalf * 8192 + sttid * 32 + 16) = *(const uint4*)(s0 + 16);
  }
  const size_t tstep = (size_t)(GG * 16);
  uint4 mv0 = *(const uint4*)(mr0 + (size_t)(kh * 8) * tstep);
  uint4 mv1 = *(const uint4*)(mr1 + (size_t)(kh * 8) * tstep);
  __syncthreads();

  for (int it = 0; it < 8; ++it) {
    uint4 ns0, ns1, nm0, nm1;
    if (it < 7) {                       // prefetch next stage (in flight all compute)
      const u8* ns = kvsrc + (size_t)(sthalf * 8 + it + 1) * 8192 + sttid * 32;
      ns0 = *(const uint4*)ns;
      ns1 = *(const uint4*)(ns + 16);
      nm0 = *(const uint4*)(mr0 + (size_t)(kh * 8 + it + 1) * tstep);
      nm1 = *(const uint4*)(mr1 + (size_t)(kh * 8 + it + 1) * tstep);
    }

    const u8* cur = kv[it & 1] + kh * 8192;
    const _Float16* ldsK = (const _Float16*)cur;
    const u8* ldsV = cur + 4096;
    u64 wa0 = ((u64)mv0.x | ((u64)mv0.y << 32)) >> shq;  // q-row 0, keys 0..63
    u64 wa1 = ((u64)mv0.z | ((u64)mv0.w << 32)) >> shq;  // q-row 0, keys 64..127
    u64 wb0 = ((u64)mv1.x | ((u64)mv1.y << 32)) >> shq;
    u64 wb1 = ((u64)mv1.z | ((u64)mv1.w << 32)) >> shq;

    #pragma unroll
    for (int st = 0; st < 8; ++st) {
      // shared fragments: K rows + chunk-swizzled V^T row (both ds_read_b64)
      h4 kf = *(const h4*)(ldsK + (size_t)(st * 16 + col) * 16 + quad * 4);
      h4 vf = *(const h4*)(ldsV + col * 256 + (((st * 4 + quad + col) & 31) * 8));

      f32x4 s0 = MFMA16(kf, qf0, cinit);      // two independent chains
      f32x4 s1 = MFMA16(kf, qf1, cinit);
      const int sh = (st & 3) * 16;
      u32 b0 = (u32)(((st < 4) ? wa0 : wa1) >> sh) & 0xFu;
      u32 b1 = (u32)(((st < 4) ? wb0 : wb1) >> sh) & 0xFu;

      float a0 = (b0 & 1u) ? 0.f : EXP2F(s0[0]);
      float a1 = (b0 & 2u) ? 0.f : EXP2F(s0[1]);
      float a2 = (b0 & 4u) ? 0.f : EXP2F(s0[2]);
      float a3 = (b0 & 8u) ? 0.f : EXP2F(s0[3]);
      float c0 = (b1 & 1u) ? 0.f : EXP2F(s1[0]);
      float c1 = (b1 & 2u) ? 0.f : EXP2F(s1[1]);
      float c2 = (b1 & 4u) ? 0.f : EXP2F(s1[2]);
      float c3 = (b1 & 8u) ? 0.f : EXP2F(s1[3]);

      h2 pa01 = __builtin_bit_cast(h2, __builtin_amdgcn_cvt_pkrtz(a0, a1));
      h2 pa23 = __builtin_bit_cast(h2, __builtin_amdgcn_cvt_pkrtz(a2, a3));
      h4 pf0 = __builtin_shufflevector(pa01, pa23, 0, 1, 2, 3);
      h2 pc01 = __builtin_bit_cast(h2, __builtin_amdgcn_cvt_pkrtz(c0, c1));
      h2 pc23 = __builtin_bit_cast(h2, __builtin_amdgcn_cvt_pkrtz(c2, c3));
      h4 pf1 = __builtin_shufflevector(pc01, pc23, 0, 1, 2, 3);

      acc0  = MFMA16(vf, pf0, acc0);          // O^T[vdim][q]
      acc1  = MFMA16(vf, pf1, acc1);
      lacc0 = MFMA16(ones, pf0, lacc0);       // denominators (MFMA pipe)
      lacc1 = MFMA16(ones, pf1, lacc1);
    }

    if (it < 7) {
      u8* nb = kv[(it + 1) & 1] + sthalf * 8192;
      *(uint4*)(nb + sttid * 32) = ns0;
      *(uint4*)(nb + sttid * 32 + 16) = ns1;
      mv0 = nm0; mv1 = nm1;
      __syncthreads();
    }
  }

  // split-K merge (r9-verified): half 0 publishes, half 1 combines + stores
  const float l0 = lacc0[0], l1 = lacc1[0];
  if (kh == 0) {
    #pragma unroll
    for (int r = 0; r < 4; ++r) {
      Lacc[g][col][shq + r]      = acc0[r];
      Lacc[g][col + 16][shq + r] = acc1[r];
    }
    if (quad == 0) { Ll[g][col] = l0; Ll[g][col + 16] = l1; }
  }
  __syncthreads();
  if (kh == 1) {
    float la = Ll[g][col] + l0;
    float lb = Ll[g][col + 16] + l1;
    float ra = (la > 0.f) ? (1.f / la) : 0.f;   // all-masked row -> 0 (ref)
    float rb = (lb > 0.f) ? (1.f / lb) : 0.f;
    float4 o0, o1;
    o0.x = (Lacc[g][col][shq + 0] + acc0[0]) * ra;
    o0.y = (Lacc[g][col][shq + 1] + acc0[1]) * ra;
    o0.z = (Lacc[g][col][shq + 2] + acc0[2]) * ra;
    o0.w = (Lacc[g][col][shq + 3] + acc0[3]) * ra;
    o1.x = (Lacc[g][col + 16][shq + 0] + acc1[0]) * rb;
    o1.y = (Lacc[g][col + 16][shq + 1] + acc1[1]) * rb;
    o1.z = (Lacc[g][col + 16][shq + 2] + acc1[2]) * rb;
    o1.w = (Lacc[g][col + 16][shq + 3] + acc1[3]) * rb;
    *(float4*)(out + ((size_t)bh * GG + qb + col) * 16 + shq) = o0;
    *(float4*)(out + ((size_t)bh * GG + qb + 16 + col) * 16 + shq) = o1;
  }
}

// ---------------------------------------------------------------------------
extern "C" void kernel_launch(void* const* d_in, const int* in_sizes, int n_in,
                              void* d_out, int out_size, void* d_ws, size_t ws_size,
                              hipStream_t stream) {
  const float* h    = (const float*)d_in[0];
  const int*   mask = (const int*)d_in[1];
  const float* WQ   = (const float*)d_in[2];
  const float* WK   = (const float*)d_in[3];
  const float* WV   = (const float*)d_in[4];
  float* out = (float*)d_out;
  char* ws = (char*)d_ws;     // uses 6.5 MB
  _Float16* Qh  = (_Float16*)(ws + OFF_Q);
  u8*       KVp = (u8*)(ws + OFF_KV);
  u8*       mbt = (u8*)(ws + OFF_M);

  hipLaunchKernelGGL(prep_kernel, dim3(256 + GG * GG / (256 * 8)), dim3(256), 0, stream,
                     h, mask, WQ, WK, WV, Qh, KVp, mbt);
  hipLaunchKernelGGL(attn_kernel, dim3(BH * (GG / 128)), dim3(512), 0, stream,
                     Qh, KVp, mbt, out);
}

// Round 14
// 107.414 us; speedup vs baseline: 1.0484x; 1.0036x over previous
//
#include <hip/hip_runtime.h>
#include <hip/hip_bf16.h>

// Problem constants (B,G,D,H,K,V) = (4, 2048, 128, 8, 16, 16)
#define GG 2048
#define DD 128
#define HH 8
#define BH 32

typedef _Float16 h2 __attribute__((ext_vector_type(2)));
typedef _Float16 h4 __attribute__((ext_vector_type(4)));
typedef _Float16 h8 __attribute__((ext_vector_type(8)));
typedef __attribute__((ext_vector_type(4))) float f32x4;
typedef unsigned short u16;
typedef unsigned int   u32;
typedef unsigned char  u8;
typedef unsigned long long u64;

// 0.25 (=1/sqrt(16)) * log2(e): folded into W_Q so softmax uses raw exp2.
#define QSCALE 0.36067376022224085f

// ws layout: 6.5 MB
#define OFF_Q  0u           // f16 Qh [BH][G][16] (scaled)                    2 MB
#define OFF_KV (2u << 20)   // u8  KVp [BH][16 tiles][8192]: K(128x16) | V^T  4 MB
#define OFF_M  (6u << 20)   // u8  mbt [16][G][16] transposed mask bits     512 KB

#if __has_builtin(__builtin_amdgcn_exp2f)
#define EXP2F(x) __builtin_amdgcn_exp2f(x)
#else
#define EXP2F(x) exp2f(x)
#endif

// Legacy K=16 f16 MFMA (no underscore before f16 — gfx908-era naming).
#define MFMA16(a, b, c) __builtin_amdgcn_mfma_f32_16x16x16f16(a, b, c, 0, 0, 0)

static __device__ __forceinline__ u16 f16b(float x) {
  return __builtin_bit_cast(u16, (_Float16)x);
}

// ---------------------------------------------------------------------------
// Kernel 1 (fused prep): unchanged from rounds 10-12 (verified).
//  blocks [0,256):   MFMA projection -> Qh + packed KV tiles (8 KB per
//                    (bh, 128-key tile): K [128][16] f16 | V^T [16][128]
//                    chunk-swizzled).
//  blocks [256,2304): mask int32 -> transposed byte map mbt[g8][q][16].
// ---------------------------------------------------------------------------
__global__ __launch_bounds__(256) void prep_kernel(
    const float* __restrict__ h, const int* __restrict__ mask,
    const float* __restrict__ WQ, const float* __restrict__ WK,
    const float* __restrict__ WV,
    _Float16* __restrict__ Qh, u8* __restrict__ KVp, u8* __restrict__ mbt)
{
  const int blk = blockIdx.x, tid = threadIdx.x;

  if (blk >= 256) {                      // ---- mask -> transposed byte map ----
    int t = (blk - 256) * 256 + tid;     // [0, 524288)
    const int* m = mask + (size_t)t * 8;
    int4 m0 = *(const int4*)m;
    int4 m1 = *(const int4*)(m + 4);
    u32 byte = (m0.x > 0) | ((m0.y > 0) << 1) | ((m0.z > 0) << 2) | ((m0.w > 0) << 3)
             | ((m1.x > 0) << 4) | ((m1.y > 0) << 5) | ((m1.z > 0) << 6) | ((m1.w > 0) << 7);
    int q  = t >> 8;          // mask row
    int k8 = t & 255;         // byte index within row (keys k8*8..+7)
    mbt[(size_t)(k8 >> 4) * (GG * 16) + (size_t)q * 16 + (k8 & 15)] = (u8)byte;
    return;
  }

  // ---- projection: 8 blocks/bh, 4 waves/block, 64 g-rows/wave ----
  __shared__ _Float16 Wl[48 * 136];      // [n 48][d 128 pad 136]
  const int bh = blk >> 3, b = bh >> 3, hh = bh & (HH - 1);

  #pragma unroll
  for (int m = 0; m < 3; ++m) {
    const float* W = (m == 0 ? WQ : (m == 1 ? WK : WV)) + (size_t)hh * DD * 16;
    const float sc = (m == 0) ? QSCALE : 1.0f;
    #pragma unroll
    for (int i = 0; i < 2; ++i) {
      int j4 = i * 256 + tid;
      float4 v = ((const float4*)W)[j4];
      int j = j4 * 4, d = j >> 4, n0 = m * 16 + (j & 15);
      Wl[(n0 + 0) * 136 + d] = (_Float16)(v.x * sc);
      Wl[(n0 + 1) * 136 + d] = (_Float16)(v.y * sc);
      Wl[(n0 + 2) * 136 + d] = (_Float16)(v.z * sc);
      Wl[(n0 + 3) * 136 + d] = (_Float16)(v.w * sc);
    }
  }
  __syncthreads();

  const int wave = tid >> 6, lane = tid & 63;
  const int col = lane & 15, quad = lane >> 4;
  const int g0 = ((blk & 7) * 4 + wave) * 64;
  const float* hb = h + (size_t)b * GG * DD;

  f32x4 acc[4][3];
  #pragma unroll
  for (int mt = 0; mt < 4; ++mt)
    #pragma unroll
    for (int nt = 0; nt < 3; ++nt)
      acc[mt][nt] = (f32x4){0.f, 0.f, 0.f, 0.f};

  #pragma unroll
  for (int s = 0; s < 4; ++s) {
    h8 a[4], bw[3];
    #pragma unroll
    for (int mt = 0; mt < 4; ++mt) {
      const float* src = hb + (size_t)(g0 + mt * 16 + col) * DD + s * 32 + quad * 8;
      float4 x = ((const float4*)src)[0];
      float4 y = ((const float4*)src)[1];
      a[mt] = (h8){ (_Float16)x.x, (_Float16)x.y, (_Float16)x.z, (_Float16)x.w,
                    (_Float16)y.x, (_Float16)y.y, (_Float16)y.z, (_Float16)y.w };
    }
    #pragma unroll
    for (int nt = 0; nt < 3; ++nt)
      bw[nt] = *(const h8*)&Wl[(nt * 16 + col) * 136 + s * 32 + quad * 8];
    #pragma unroll
    for (int mt = 0; mt < 4; ++mt)
      #pragma unroll
      for (int nt = 0; nt < 3; ++nt)
        acc[mt][nt] = __builtin_amdgcn_mfma_f32_16x16x32_f16(a[mt], bw[nt], acc[mt][nt], 0, 0, 0);
  }

  u8* kvb = KVp + (size_t)bh * 16 * 8192;
  #pragma unroll
  for (int mt = 0; mt < 4; ++mt) {
    #pragma unroll
    for (int r = 0; r < 4; ++r) {
      int g = g0 + mt * 16 + quad * 4 + r;
      Qh[((size_t)bh * GG + g) * 16 + col] = (_Float16)acc[mt][0][r];
      int gi = g & 127;
      u8* tb = kvb + (size_t)(g >> 7) * 8192;
      *(u16*)(tb + gi * 32 + col * 2) = f16b(acc[mt][1][r]);                 // K
      *(u16*)(tb + 4096 + col * 256 + ((((gi >> 2) + col) & 31) * 8)
                 + (g & 3) * 2) = f16b(acc[mt][2][r]);                       // V^T swizzled
    }
  }
}

// ---------------------------------------------------------------------------
// Kernel 2: flash attention — 8 waves/SIMD (HW max) + mask-in-C-operand.
// 1024-thr blocks (16 waves = 8 q-tiles x 2 key-halves) covering 128 q each;
// grid = BH * GG/128 = 512 blocks = 2 blocks/CU = 32 waves/CU = 8 waves/SIMD.
// (r13 FAILED on grid math: blocks covered 128 q but grid allotted 256 —
// half the output never written. Fixed here; numerics unchanged.)
// __launch_bounds__(1024,8) caps VGPR at 64; each wave runs ONE lean chain
// (16 q, 1024 keys) — TLP replaces r12's 2-chain ILP at 2x chains/SIMD.
// Mask folds into the S-MFMA C operand (masked -> -3000: v_exp_f32
// underflows to exact +0, identical semantics) — post-exp cndmasks vanish
// from the dependency chain. LDS staging (r10) + ones-MFMA denominator (r9)
// + split-K LDS merge (r9) + XCD swizzle (r8) all retained.
// ---------------------------------------------------------------------------
__global__ __launch_bounds__(1024, 8) void attn_kernel(
    const _Float16* __restrict__ Qh, const u8* __restrict__ KVp,
    const u8* __restrict__ mbt, float* __restrict__ out)
{
  __shared__ __align__(16) u8 kv[2][16384];   // [stage parity][half0 8KB|half1 8KB]
  __shared__ float Lacc[8][16][17];           // merge: [q-tile][q][vdim pad]
  __shared__ float Ll[8][16];
  const int tid = threadIdx.x, wv = tid >> 6, lane = tid & 63;
  const int col = lane & 15, quad = lane >> 4;
  const int qt = wv & 7;               // q-tile index (16 q each)
  const int kh = wv >> 3;              // key half (0: keys 0..1023, 1: rest)
  const int bh = blockIdx.x & 31;      // XCD swizzle: same bh -> same XCD
  const int qb = (blockIdx.x >> 5) * 128 + qt * 16;   // 128 q per block (FIX)

  // Q B-frag (16x16x16): n=col, k=quad*4+j -> 8B load
  const h4 qf = *(const h4*)(Qh + ((size_t)bh * GG + qb + col) * 16 + quad * 4);
  const u8* kvsrc = KVp + (size_t)bh * 16 * 8192;
  const u8* mrow  = mbt + (size_t)(qb + col) * 16;

  f32x4 acc = {0.f,0.f,0.f,0.f}, lacc = {0.f,0.f,0.f,0.f};
  const h4 ones = {(_Float16)1.f, (_Float16)1.f, (_Float16)1.f, (_Float16)1.f};
  const int shq = quad * 4;

  // staging role: threads 0-511 stage half-0 tiles (it), 512-1023 half-1 (8+it)
  const int sh2 = tid >> 9, stid = tid & 511;   // 512 thr x 16 B = 8 KB tile

  // prologue: stage tiles {0, 8} + this wave's tile-0 mask
  *(uint4*)(kv[0] + sh2 * 8192 + stid * 16) =
      *(const uint4*)(kvsrc + (size_t)(sh2 * 8) * 8192 + stid * 16);
  const size_t tstep = (size_t)(GG * 16);
  uint4 mv = *(const uint4*)(mrow + (size_t)(kh * 8) * tstep);
  __syncthreads();

  for (int it = 0; it < 8; ++it) {
    uint4 ns, nm;
    if (it < 7) {                      // prefetch next stage (in flight all compute)
      ns = *(const uint4*)(kvsrc + (size_t)(sh2 * 8 + it + 1) * 8192 + stid * 16);
      nm = *(const uint4*)(mrow + (size_t)(kh * 8 + it + 1) * tstep);
    }

    const u8* cur = kv[it & 1] + kh * 8192;
    const _Float16* ldsK = (const _Float16*)cur;
    const u8* ldsV = cur + 4096;
    u64 w0 = ((u64)mv.x | ((u64)mv.y << 32)) >> shq;   // keys 0..63, pre-shifted
    u64 w1 = ((u64)mv.z | ((u64)mv.w << 32)) >> shq;   // keys 64..127

    #pragma unroll
    for (int st = 0; st < 8; ++st) {
      // K rows + chunk-swizzled V^T row (both ds_read_b64, conflict-floor)
      h4 kf = *(const h4*)(ldsK + (size_t)(st * 16 + col) * 16 + quad * 4);
      h4 vf = *(const h4*)(ldsV + col * 256 + (((st * 4 + quad + col) & 31) * 8));

      // mask -> C operand: masked reg -> -3000 (exp2 underflows to exact +0),
      // unmasked -> -4 (uniform shift, cancels in softmax). Off the S->P chain.
      u32 bits = (u32)(((st < 4) ? w0 : w1) >> ((st & 3) * 16)) & 0xFu;
      f32x4 cm;
      cm[0] = (bits & 1u) ? -3000.f : -4.f;
      cm[1] = (bits & 2u) ? -3000.f : -4.f;
      cm[2] = (bits & 4u) ? -3000.f : -4.f;
      cm[3] = (bits & 8u) ? -3000.f : -4.f;

      f32x4 s = MFMA16(kf, qf, cm);            // S^T[key=quad*4+r][q=col]
      float p0 = EXP2F(s[0]);
      float p1 = EXP2F(s[1]);
      float p2 = EXP2F(s[2]);
      float p3 = EXP2F(s[3]);

      h2 a01 = __builtin_bit_cast(h2, __builtin_amdgcn_cvt_pkrtz(p0, p1));
      h2 a23 = __builtin_bit_cast(h2, __builtin_amdgcn_cvt_pkrtz(p2, p3));
      h4 pf = __builtin_shufflevector(a01, a23, 0, 1, 2, 3);

      acc  = MFMA16(vf, pf, acc);              // O^T[vdim][q]
      lacc = MFMA16(ones, pf, lacc);           // denominator (MFMA pipe)
    }

    if (it < 7) {
      *(uint4*)(kv[(it + 1) & 1] + sh2 * 8192 + stid * 16) = ns;
      mv = nm;
      __syncthreads();
    }
  }

  // split-K merge: half 0 publishes partials, half 1 combines + stores
  const float l = lacc[0];                     // sum_k P[k][col], this half
  if (kh == 0) {
    #pragma unroll
    for (int r = 0; r < 4; ++r) Lacc[qt][col][shq + r] = acc[r];
    if (quad == 0) Ll[qt][col] = l;
  }
  __syncthreads();
  if (kh == 1) {
    float la = Ll[qt][col] + l;
    float ra = (la > 0.f) ? (1.f / la) : 0.f;  // all-masked row -> 0 (ref)
    float4 o;
    o.x = (Lacc[qt][col][shq + 0] + acc[0]) * ra;
    o.y = (Lacc[qt][col][shq + 1] + acc[1]) * ra;
    o.z = (Lacc[qt][col][shq + 2] + acc[2]) * ra;
    o.w = (Lacc[qt][col][shq + 3] + acc[3]) * ra;
    *(float4*)(out + ((size_t)bh * GG + qb + col) * 16 + shq) = o;
  }
}

// ---------------------------------------------------------------------------
extern "C" void kernel_launch(void* const* d_in, const int* in_sizes, int n_in,
                              void* d_out, int out_size, void* d_ws, size_t ws_size,
                              hipStream_t stream) {
  const float* h    = (const float*)d_in[0];
  const int*   mask = (const int*)d_in[1];
  const float* WQ   = (const float*)d_in[2];
  const float* WK   = (const float*)d_in[3];
  const float* WV   = (const float*)d_in[4];
  float* out = (float*)d_out;
  char* ws = (char*)d_ws;     // uses 6.5 MB
  _Float16* Qh  = (_Float16*)(ws + OFF_Q);
  u8*       KVp = (u8*)(ws + OFF_KV);
  u8*       mbt = (u8*)(ws + OFF_M);

  hipLaunchKernelGGL(prep_kernel, dim3(256 + GG * GG / (256 * 8)), dim3(256), 0, stream,
                     h, mask, WQ, WK, WV, Qh, KVp, mbt);
  hipLaunchKernelGGL(attn_kernel, dim3(BH * (GG / 128)), dim3(1024), 0, stream,
                     Qh, KVp, mbt, out);
}